// Round 1
// baseline (126.650 us; speedup 1.0000x reference)
//
#include <hip/hip_runtime.h>
#include <math.h>

#define PMAX 10
#define CCH 515
#define CENTER_CH 514
#define HH 128
#define WW 128
#define HW (HH * WW)
#define VAL_TH 0.3f

// ---------------------------------------------------------------------------
// Kernel A: NMS (5x5 maxpool SAME, keep-if-equal) + top-10 per (n,v) heatmap.
// One block per heatmap. Heatmap staged in 64KB LDS; per-thread register
// top-10 (statically unrolled insertion, stays in VGPRs); merge via LDS
// (reusing hm buffer) with 10 block-wide argmax rounds.
// ---------------------------------------------------------------------------
__global__ __launch_bounds__(256) void nms_topk_kernel(
    const float* __restrict__ fmap, float* __restrict__ out_valk, int C) {
    __shared__ float hm[HW];  // 64 KB
    const int b = blockIdx.x;
    const int tid = threadIdx.x;

    const float* src = fmap + ((size_t)b * C + CENTER_CH) * HW;
    for (int i = tid; i < HW; i += 256) hm[i] = src[i];
    __syncthreads();

    // Per-thread sorted (descending) top-10 in registers.
    float t0 = -INFINITY, t1 = -INFINITY, t2 = -INFINITY, t3 = -INFINITY,
          t4 = -INFINITY, t5 = -INFINITY, t6 = -INFINITY, t7 = -INFINITY,
          t8 = -INFINITY, t9 = -INFINITY;

    for (int i = tid; i < HW; i += 256) {
        const int y = i >> 7;
        const int x = i & (WW - 1);
        const float v = hm[i];
        float m = v;
        const int ylo = max(y - 2, 0), yhi = min(y + 2, HH - 1);
        const int xlo = max(x - 2, 0), xhi = min(x + 2, WW - 1);
        for (int yy = ylo; yy <= yhi; ++yy) {
            const int row = yy << 7;
            for (int xx = xlo; xx <= xhi; ++xx) m = fmaxf(m, hm[row + xx]);
        }
        float nv = (m == v) ? v : 0.0f;  // exact-equality NMS, matches reference

        // Branchless sorted insert (static indices -> registers).
        bool g;
        float a;
#define INS(tk)                      \
        a = tk;                      \
        g = nv > a;                  \
        tk = g ? nv : a;             \
        nv = g ? a : nv;
        INS(t0) INS(t1) INS(t2) INS(t3) INS(t4)
        INS(t5) INS(t6) INS(t7) INS(t8) INS(t9)
#undef INS
    }
    __syncthreads();  // done reading hm; reuse it as candidate buffer

    // 256 threads x 10 candidates = 2560 entries at hm[0..2560)
    {
        float* tp = &hm[tid * 10];
        tp[0] = t0; tp[1] = t1; tp[2] = t2; tp[3] = t3; tp[4] = t4;
        tp[5] = t5; tp[6] = t6; tp[7] = t7; tp[8] = t8; tp[9] = t9;
    }
    __syncthreads();

    // 10 rounds of block-wide argmax over the 2560 candidates.
    for (int r = 0; r < 10; ++r) {
        float bv = -INFINITY;
        int bi = 0;
        for (int i = tid; i < 2560; i += 256) {
            float v = hm[i];
            if (v > bv) { bv = v; bi = i; }
        }
        for (int off = 32; off; off >>= 1) {
            float ov = __shfl_down(bv, off);
            int oi = __shfl_down(bi, off);
            if (ov > bv) { bv = ov; bi = oi; }
        }
        if ((tid & 63) == 0) {
            hm[2560 + (tid >> 6)] = bv;
            hm[2564 + (tid >> 6)] = __int_as_float(bi);
        }
        __syncthreads();
        if (tid == 0) {
            float fbv = hm[2560];
            int fbi = __float_as_int(hm[2564]);
            for (int w = 1; w < 4; ++w) {
                float v = hm[2560 + w];
                if (v > fbv) { fbv = v; fbi = __float_as_int(hm[2564 + w]); }
            }
            out_valk[b * PMAX + r] = (fbv < VAL_TH) ? 0.0f : fbv;
            hm[fbi] = -INFINITY;  // remove selected candidate
        }
        __syncthreads();
    }
}

// ---------------------------------------------------------------------------
// Kernel B: bilinear grid-sample of all C channels at one (b,p) point per
// block. Matches reference clip/floor/weight algebra exactly.
// ---------------------------------------------------------------------------
__global__ __launch_bounds__(256) void sample_kernel(
    const float* __restrict__ fmap, const float* __restrict__ centers,
    float* __restrict__ out_nf, int C) {
    const int bp = blockIdx.x;  // b*PMAX + p
    const int b = bp / PMAX;

    const float x = centers[bp * 3 + 0];
    const float y = centers[bp * 3 + 1];
    const float x0f = floorf(x), y0f = floorf(y);
    const float wx = x - x0f, wy = y - y0f;
    int x0 = min(max((int)x0f, 0), WW - 1);
    int x1 = min(x0 + 1, WW - 1);
    int y0 = min(max((int)y0f, 0), HH - 1);
    int y1 = min(y0 + 1, HH - 1);

    const float w00 = (1.0f - wx) * (1.0f - wy);
    const float w01 = wx * (1.0f - wy);
    const float w10 = (1.0f - wx) * wy;
    const float w11 = wx * wy;

    const int o00 = y0 * WW + x0, o01 = y0 * WW + x1;
    const int o10 = y1 * WW + x0, o11 = y1 * WW + x1;

    const float* base = fmap + (size_t)b * C * HW;
    for (int c = threadIdx.x; c < C; c += 256) {
        const float* f = base + (size_t)c * HW;
        float r = w00 * f[o00] + w01 * f[o01] + w10 * f[o10] + w11 * f[o11];
        out_nf[(size_t)bp * C + c] = r;
    }
}

// ---------------------------------------------------------------------------
// Kernel C: weighted BCE over valid edges. Single block, two-phase reduce.
// ---------------------------------------------------------------------------
__global__ __launch_bounds__(256) void loss_kernel(
    const float* __restrict__ logits, const float* __restrict__ labels,
    const float* __restrict__ valid, float* __restrict__ out_loss, int E) {
    __shared__ float red[8];
    const int tid = threadIdx.x;

    // Phase 1: num_pos = sum(labels*valid), num_valid = sum(valid)
    float sp = 0.0f, sv = 0.0f;
    for (int i = tid; i < E; i += 256) {
        const float l = labels[i], v = valid[i];
        sp += l * v;
        sv += v;
    }
    for (int off = 32; off; off >>= 1) {
        sp += __shfl_down(sp, off);
        sv += __shfl_down(sv, off);
    }
    if ((tid & 63) == 0) {
        red[tid >> 6] = sp;
        red[4 + (tid >> 6)] = sv;
    }
    __syncthreads();
    const float num_pos = red[0] + red[1] + red[2] + red[3];
    const float num_valid = red[4] + red[5] + red[6] + red[7];
    const float num_neg = num_valid - num_pos;
    const float wp = 1.0f / (num_pos + 1e-12f);
    const float wn = 1.0f / (num_neg + 1e-12f);
    __syncthreads();  // everyone has read red[] before reuse

    // Phase 2: loss = sum(bce * w * valid)
    float acc = 0.0f;
    for (int i = tid; i < E; i += 256) {
        const float xl = logits[i], lab = labels[i], v = valid[i];
        const float sm = log1pf(expf(-fabsf(xl)));
        const float logp = fminf(xl, 0.0f) - sm;    // log_sigmoid(x)
        const float log1mp = -fmaxf(xl, 0.0f) - sm; // log_sigmoid(-x)
        const float bce = -(lab * logp + (1.0f - lab) * log1mp);
        const float w = (lab > 0.0f) ? wp : wn;
        acc += bce * w * v;
    }
    for (int off = 32; off; off >>= 1) acc += __shfl_down(acc, off);
    if ((tid & 63) == 0) red[tid >> 6] = acc;
    __syncthreads();
    if (tid == 0) out_loss[0] = red[0] + red[1] + red[2] + red[3];
}

// ---------------------------------------------------------------------------
extern "C" void kernel_launch(void* const* d_in, const int* in_sizes, int n_in,
                              void* d_out, int out_size, void* d_ws, size_t ws_size,
                              hipStream_t stream) {
    const float* fmap    = (const float*)d_in[0];
    const float* centers = (const float*)d_in[1];
    const float* logits  = (const float*)d_in[2];
    const float* labels  = (const float*)d_in[3];
    const float* valid   = (const float*)d_in[4];
    float* out = (float*)d_out;

    const int C = CCH;
    const int NV = in_sizes[0] / (C * HW);  // N*V = 10
    const int E = in_sizes[2];              // 2000

    // Output layout: val_k [NV*PMAX] | node_features [NV*PMAX*C] | loss [1]
    float* out_valk = out;
    float* out_nf   = out + NV * PMAX;
    float* out_loss = out + NV * PMAX + (size_t)NV * PMAX * C;

    nms_topk_kernel<<<NV, 256, 0, stream>>>(fmap, out_valk, C);
    sample_kernel<<<NV * PMAX, 256, 0, stream>>>(fmap, centers, out_nf, C);
    loss_kernel<<<1, 256, 0, stream>>>(logits, labels, valid, out_loss, E);
}

// Round 2
// 31.458 us; speedup vs baseline: 4.0260x; 4.0260x over previous
//
#include <hip/hip_runtime.h>
#include <math.h>

#define PMAX 10
#define CCH 515
#define CENTER_CH 514
#define HH 128
#define WW 128
#define HW (HH * WW)
#define VAL_TH 0.3f
#define NTHR 1024

// One fused kernel. Block roles:
//   blocks [0, NV)            : NMS 5x5 + top-10 for heatmap b  (uses 64KB LDS)
//   blocks [NV, NV+NV*PMAX)   : bilinear grid-sample for point (b,p)
//   block  NV+NV*PMAX         : weighted BCE loss
__global__ __launch_bounds__(NTHR) void fused_kernel(
    const float* __restrict__ fmap, const float* __restrict__ centers,
    const float* __restrict__ logits, const float* __restrict__ labels,
    const float* __restrict__ valid,
    float* __restrict__ out_valk, float* __restrict__ out_nf,
    float* __restrict__ out_loss, int C, int NV, int E) {
    __shared__ float hm[HW];  // 64 KB; reused as candidate buffer / reduce scratch
    const int blk = blockIdx.x;
    const int tid = threadIdx.x;

    if (blk < NV) {
        // ------------------- NMS + top-10 -------------------
        const float* src = fmap + ((size_t)blk * C + CENTER_CH) * HW;
        for (int i = tid; i < HW; i += NTHR) hm[i] = src[i];
        __syncthreads();

        float t0 = -INFINITY, t1 = -INFINITY, t2 = -INFINITY, t3 = -INFINITY,
              t4 = -INFINITY, t5 = -INFINITY, t6 = -INFINITY, t7 = -INFINITY,
              t8 = -INFINITY, t9 = -INFINITY;

        for (int k = 0; k < HW / NTHR; ++k) {
            const int i = tid + k * NTHR;
            const int y = i >> 7;
            const int x = i & (WW - 1);
            const float v = hm[i];
            // Clamped row bases / col offsets; clamp revisits in-range pixels,
            // max is idempotent -> identical to SAME-window maxpool.
            const int r0 = max(y - 2, 0) << 7, r1 = max(y - 1, 0) << 7, r2 = y << 7,
                      r3 = min(y + 1, HH - 1) << 7, r4 = min(y + 2, HH - 1) << 7;
            const int c0 = max(x - 2, 0), c1 = max(x - 1, 0), c2 = x,
                      c3 = min(x + 1, WW - 1), c4 = min(x + 2, WW - 1);
            float m = v;
            m = fmaxf(m, hm[r0 + c0]); m = fmaxf(m, hm[r0 + c1]); m = fmaxf(m, hm[r0 + c2]);
            m = fmaxf(m, hm[r0 + c3]); m = fmaxf(m, hm[r0 + c4]);
            m = fmaxf(m, hm[r1 + c0]); m = fmaxf(m, hm[r1 + c1]); m = fmaxf(m, hm[r1 + c2]);
            m = fmaxf(m, hm[r1 + c3]); m = fmaxf(m, hm[r1 + c4]);
            m = fmaxf(m, hm[r2 + c0]); m = fmaxf(m, hm[r2 + c1]);
            m = fmaxf(m, hm[r2 + c3]); m = fmaxf(m, hm[r2 + c4]);
            m = fmaxf(m, hm[r3 + c0]); m = fmaxf(m, hm[r3 + c1]); m = fmaxf(m, hm[r3 + c2]);
            m = fmaxf(m, hm[r3 + c3]); m = fmaxf(m, hm[r3 + c4]);
            m = fmaxf(m, hm[r4 + c0]); m = fmaxf(m, hm[r4 + c1]); m = fmaxf(m, hm[r4 + c2]);
            m = fmaxf(m, hm[r4 + c3]); m = fmaxf(m, hm[r4 + c4]);
            float nv = (m == v) ? v : 0.0f;

            if (nv > t9) {  // can only change top-10 if it beats current 10th
                bool g; float a;
#define INS(tk) a = tk; g = nv > a; tk = g ? nv : a; nv = g ? a : nv;
                INS(t0) INS(t1) INS(t2) INS(t3) INS(t4)
                INS(t5) INS(t6) INS(t7) INS(t8) INS(t9)
#undef INS
            }
        }
        __syncthreads();  // done reading heatmap; reuse hm as candidate buffer

        {   // NTHR threads x 10 candidates at hm[0 .. NTHR*10)
            float* tp = &hm[tid * 10];
            tp[0] = t0; tp[1] = t1; tp[2] = t2; tp[3] = t3; tp[4] = t4;
            tp[5] = t5; tp[6] = t6; tp[7] = t7; tp[8] = t8; tp[9] = t9;
        }
        __syncthreads();

        const int NC = NTHR * 10;  // 10240 candidates
        for (int r = 0; r < 10; ++r) {
            float bv = -INFINITY;
            int bi = 0;
            for (int i = tid; i < NC; i += NTHR) {
                float v = hm[i];
                if (v > bv) { bv = v; bi = i; }
            }
            for (int off = 32; off; off >>= 1) {
                float ov = __shfl_down(bv, off);
                int oi = __shfl_down(bi, off);
                if (ov > bv) { bv = ov; bi = oi; }
            }
            if ((tid & 63) == 0) {
                hm[NC + (tid >> 6)] = bv;
                hm[NC + 16 + (tid >> 6)] = __int_as_float(bi);
            }
            __syncthreads();
            if (tid == 0) {
                float fbv = hm[NC];
                int fbi = __float_as_int(hm[NC + 16]);
                for (int w = 1; w < NTHR / 64; ++w) {
                    float v = hm[NC + w];
                    if (v > fbv) { fbv = v; fbi = __float_as_int(hm[NC + 16 + w]); }
                }
                out_valk[blk * PMAX + r] = (fbv < VAL_TH) ? 0.0f : fbv;
                hm[fbi] = -INFINITY;
            }
            __syncthreads();
        }
    } else if (blk < NV + NV * PMAX) {
        // ------------------- bilinear grid-sample -------------------
        const int bp = blk - NV;
        const int b = bp / PMAX;
        const float x = centers[bp * 3 + 0];
        const float y = centers[bp * 3 + 1];
        const float x0f = floorf(x), y0f = floorf(y);
        const float wx = x - x0f, wy = y - y0f;
        const int x0 = min(max((int)x0f, 0), WW - 1);
        const int x1 = min(x0 + 1, WW - 1);
        const int y0 = min(max((int)y0f, 0), HH - 1);
        const int y1 = min(y0 + 1, HH - 1);
        const float w00 = (1.0f - wx) * (1.0f - wy);
        const float w01 = wx * (1.0f - wy);
        const float w10 = (1.0f - wx) * wy;
        const float w11 = wx * wy;
        const int o00 = y0 * WW + x0, o01 = y0 * WW + x1;
        const int o10 = y1 * WW + x0, o11 = y1 * WW + x1;
        const float* base = fmap + (size_t)b * C * HW;
        for (int c = tid; c < C; c += NTHR) {
            const float* f = base + (size_t)c * HW;
            out_nf[(size_t)bp * C + c] =
                w00 * f[o00] + w01 * f[o01] + w10 * f[o10] + w11 * f[o11];
        }
    } else {
        // ------------------- weighted BCE loss (single pass) -------------------
        float sp = 0.0f, sv = 0.0f, bpos = 0.0f, bneg = 0.0f;
        for (int i = tid; i < E; i += NTHR) {
            const float xl = logits[i], lab = labels[i], v = valid[i];
            sp += lab * v;
            sv += v;
            const float sm = log1pf(expf(-fabsf(xl)));
            const float logp = fminf(xl, 0.0f) - sm;     // log_sigmoid(x)
            const float log1mp = -fmaxf(xl, 0.0f) - sm;  // log_sigmoid(-x)
            const float bce = -(lab * logp + (1.0f - lab) * log1mp);
            const float bv = bce * v;
            if (lab > 0.0f) bpos += bv; else bneg += bv;
        }
        for (int off = 32; off; off >>= 1) {
            sp += __shfl_down(sp, off);
            sv += __shfl_down(sv, off);
            bpos += __shfl_down(bpos, off);
            bneg += __shfl_down(bneg, off);
        }
        const int w = tid >> 6;  // 16 waves
        if ((tid & 63) == 0) {
            hm[w] = sp; hm[16 + w] = sv; hm[32 + w] = bpos; hm[48 + w] = bneg;
        }
        __syncthreads();
        if (tid == 0) {
            float tsp = 0, tsv = 0, tbp = 0, tbn = 0;
            for (int i = 0; i < NTHR / 64; ++i) {
                tsp += hm[i]; tsv += hm[16 + i]; tbp += hm[32 + i]; tbn += hm[48 + i];
            }
            const float num_neg = tsv - tsp;
            out_loss[0] = tbp / (tsp + 1e-12f) + tbn / (num_neg + 1e-12f);
        }
    }
}

extern "C" void kernel_launch(void* const* d_in, const int* in_sizes, int n_in,
                              void* d_out, int out_size, void* d_ws, size_t ws_size,
                              hipStream_t stream) {
    const float* fmap    = (const float*)d_in[0];
    const float* centers = (const float*)d_in[1];
    const float* logits  = (const float*)d_in[2];
    const float* labels  = (const float*)d_in[3];
    const float* valid   = (const float*)d_in[4];
    float* out = (float*)d_out;

    const int C = CCH;
    const int NV = in_sizes[0] / (C * HW);  // N*V = 10
    const int E = in_sizes[2];              // 2000

    float* out_valk = out;
    float* out_nf   = out + NV * PMAX;
    float* out_loss = out + NV * PMAX + (size_t)NV * PMAX * C;

    const int grid = NV + NV * PMAX + 1;  // 111
    fused_kernel<<<grid, NTHR, 0, stream>>>(fmap, centers, logits, labels, valid,
                                            out_valk, out_nf, out_loss, C, NV, E);
}

// Round 3
// 16.266 us; speedup vs baseline: 7.7863x; 1.9340x over previous
//
#include <hip/hip_runtime.h>
#include <math.h>

#define PMAX 10
#define CCH 515
#define CENTER_CH 514
#define HH 128
#define WW 128
#define HW (HH * WW)
#define VAL_TH 0.3f
#define NTHR 1024
#define CAP 4096

// One fused kernel. Block roles:
//   blocks [0, NV)          : NMS 5x5 (separable, register-blocked) + top-10
//   blocks [NV, NV+NV*PMAX) : bilinear grid-sample for point (b,p)
//   block  NV+NV*PMAX       : weighted BCE loss
__global__ __launch_bounds__(NTHR) void fused_kernel(
    const float* __restrict__ fmap, const float* __restrict__ centers,
    const float* __restrict__ logits, const float* __restrict__ labels,
    const float* __restrict__ valid,
    float* __restrict__ out_valk, float* __restrict__ out_nf,
    float* __restrict__ out_loss, int C, int NV, int E) {
    __shared__ float hmv[HW];    // 64 KB: heatmap values
    __shared__ float rmx[HW];    // 64 KB: 5-wide row max
    __shared__ float cand[CAP];  // 16 KB: peak candidates >= TH (loss reuses)
    __shared__ int cnt;
    const int blk = blockIdx.x;
    const int tid = threadIdx.x;

    if (blk < NV) {
        // ---------- Phase A: load row segment to regs, compute 5-wide row max
        const float* src = fmap + ((size_t)blk * C + CENTER_CH) * HW;
        const int y = tid >> 3;          // 0..127
        const int x0 = (tid & 7) << 4;   // 0,16,...,112
        const float* row = src + y * WW;

        if (tid == 0) cnt = 0;

        float h[20];  // h[k] = hm[y][x0 + k - 2] (cols clamped)
#pragma unroll
        for (int j = 0; j < 4; ++j) {
            const float4 f = *reinterpret_cast<const float4*>(row + x0 + 4 * j);
            h[2 + 4 * j + 0] = f.x; h[2 + 4 * j + 1] = f.y;
            h[2 + 4 * j + 2] = f.z; h[2 + 4 * j + 3] = f.w;
        }
        h[0]  = row[max(x0 - 2, 0)];
        h[1]  = row[max(x0 - 1, 0)];
        h[18] = row[min(x0 + 16, WW - 1)];
        h[19] = row[min(x0 + 17, WW - 1)];

        // stash values for the col pass / peak check
#pragma unroll
        for (int j = 0; j < 4; ++j) {
            *reinterpret_cast<float4*>(&hmv[y * WW + x0 + 4 * j]) =
                float4{h[2+4*j], h[3+4*j], h[4+4*j], h[5+4*j]};
        }

        float p[19];
#pragma unroll
        for (int k = 0; k < 19; ++k) p[k] = fmaxf(h[k], h[k + 1]);
        float rmv[16];
#pragma unroll
        for (int j = 0; j < 16; ++j)  // max(h[j..j+4])
            rmv[j] = fmaxf(fmaxf(p[j], h[j + 2]), p[j + 3]);
#pragma unroll
        for (int j = 0; j < 4; ++j) {
            *reinterpret_cast<float4*>(&rmx[y * WW + x0 + 4 * j]) =
                float4{rmv[4*j], rmv[4*j+1], rmv[4*j+2], rmv[4*j+3]};
        }
        __syncthreads();

        // ---------- Phase B: vertical strip col-max + peak compaction
        {
            const int x = tid & 127;
            const int ys = (tid >> 7) << 4;  // 0,16,...,112
            float m[20];  // m[r] = rmx[ys + r - 2][x] (rows clamped)
#pragma unroll
            for (int r = 0; r < 20; ++r)
                m[r] = rmx[min(max(ys + r - 2, 0), HH - 1) * WW + x];
            float pp[19];
#pragma unroll
            for (int r = 0; r < 19; ++r) pp[r] = fmaxf(m[r], m[r + 1]);
#pragma unroll
            for (int j = 0; j < 16; ++j) {
                const float cm = fmaxf(fmaxf(pp[j], m[j + 2]), pp[j + 3]);
                const float v = hmv[(ys + j) * WW + x];
                if (cm == v && v >= VAL_TH) {  // peak above threshold
                    const int pos = atomicAdd(&cnt, 1);
                    if (pos < CAP) cand[pos] = v;
                }
            }
        }
        __syncthreads();

        // ---------- Phase C: single-wave top-10 (no barriers)
        if (tid < 64) {
            const int n = min(cnt, CAP);
            float t0 = -INFINITY, t1 = -INFINITY, t2 = -INFINITY,
                  t3 = -INFINITY, t4 = -INFINITY, t5 = -INFINITY,
                  t6 = -INFINITY, t7 = -INFINITY, t8 = -INFINITY,
                  t9 = -INFINITY;
            for (int j = tid; j < n; j += 64) {
                float nv = cand[j];
                if (nv > t9) {
                    bool g; float a;
#define INS(tk) a = tk; g = nv > a; tk = g ? nv : a; nv = g ? a : nv;
                    INS(t0) INS(t1) INS(t2) INS(t3) INS(t4)
                    INS(t5) INS(t6) INS(t7) INS(t8) INS(t9)
#undef INS
                }
            }
            for (int r = 0; r < 10; ++r) {
                float bv = t0;
#pragma unroll
                for (int off = 32; off; off >>= 1)
                    bv = fmaxf(bv, __shfl_down(bv, off));
                bv = __shfl(bv, 0);
                const unsigned long long mask = __ballot(t0 == bv);
                const int winner = (int)(__ffsll((long long)mask) - 1);
                if (tid == winner) {  // pop my head
                    t0 = t1; t1 = t2; t2 = t3; t3 = t4; t4 = t5;
                    t5 = t6; t6 = t7; t7 = t8; t8 = t9; t9 = -INFINITY;
                }
                if (tid == 0)
                    out_valk[blk * PMAX + r] = (bv < VAL_TH) ? 0.0f : bv;
            }
        }
    } else if (blk < NV + NV * PMAX) {
        // ---------- bilinear grid-sample ----------
        const int bp = blk - NV;
        const int b = bp / PMAX;
        const float x = centers[bp * 3 + 0];
        const float y = centers[bp * 3 + 1];
        const float x0f = floorf(x), y0f = floorf(y);
        const float wx = x - x0f, wy = y - y0f;
        const int x0 = min(max((int)x0f, 0), WW - 1);
        const int x1 = min(x0 + 1, WW - 1);
        const int y0 = min(max((int)y0f, 0), HH - 1);
        const int y1 = min(y0 + 1, HH - 1);
        const float w00 = (1.0f - wx) * (1.0f - wy);
        const float w01 = wx * (1.0f - wy);
        const float w10 = (1.0f - wx) * wy;
        const float w11 = wx * wy;
        const int o00 = y0 * WW + x0, o01 = y0 * WW + x1;
        const int o10 = y1 * WW + x0, o11 = y1 * WW + x1;
        const float* base = fmap + (size_t)b * C * HW;
        for (int c = tid; c < C; c += NTHR) {
            const float* f = base + (size_t)c * HW;
            out_nf[(size_t)bp * C + c] =
                w00 * f[o00] + w01 * f[o01] + w10 * f[o10] + w11 * f[o11];
        }
    } else {
        // ---------- weighted BCE loss (single pass) ----------
        float sp = 0.0f, sv = 0.0f, bpos = 0.0f, bneg = 0.0f;
        for (int i = tid; i < E; i += NTHR) {
            const float xl = logits[i], lab = labels[i], v = valid[i];
            sp += lab * v;
            sv += v;
            const float sm = log1pf(expf(-fabsf(xl)));
            const float logp = fminf(xl, 0.0f) - sm;     // log_sigmoid(x)
            const float log1mp = -fmaxf(xl, 0.0f) - sm;  // log_sigmoid(-x)
            const float bce = -(lab * logp + (1.0f - lab) * log1mp);
            const float bv = bce * v;
            if (lab > 0.0f) bpos += bv; else bneg += bv;
        }
        for (int off = 32; off; off >>= 1) {
            sp += __shfl_down(sp, off);
            sv += __shfl_down(sv, off);
            bpos += __shfl_down(bpos, off);
            bneg += __shfl_down(bneg, off);
        }
        const int w = tid >> 6;  // 16 waves
        if ((tid & 63) == 0) {
            cand[w] = sp; cand[16 + w] = sv; cand[32 + w] = bpos; cand[48 + w] = bneg;
        }
        __syncthreads();
        if (tid == 0) {
            float tsp = 0, tsv = 0, tbp = 0, tbn = 0;
            for (int i = 0; i < NTHR / 64; ++i) {
                tsp += cand[i]; tsv += cand[16 + i];
                tbp += cand[32 + i]; tbn += cand[48 + i];
            }
            const float num_neg = tsv - tsp;
            out_loss[0] = tbp / (tsp + 1e-12f) + tbn / (num_neg + 1e-12f);
        }
    }
}

extern "C" void kernel_launch(void* const* d_in, const int* in_sizes, int n_in,
                              void* d_out, int out_size, void* d_ws, size_t ws_size,
                              hipStream_t stream) {
    const float* fmap    = (const float*)d_in[0];
    const float* centers = (const float*)d_in[1];
    const float* logits  = (const float*)d_in[2];
    const float* labels  = (const float*)d_in[3];
    const float* valid   = (const float*)d_in[4];
    float* out = (float*)d_out;

    const int C = CCH;
    const int NV = in_sizes[0] / (C * HW);  // N*V = 10
    const int E = in_sizes[2];              // 2000

    float* out_valk = out;
    float* out_nf   = out + NV * PMAX;
    float* out_loss = out + NV * PMAX + (size_t)NV * PMAX * C;

    const int grid = NV + NV * PMAX + 1;  // 111
    fused_kernel<<<grid, NTHR, 0, stream>>>(fmap, centers, logits, labels, valid,
                                            out_valk, out_nf, out_loss, C, NV, E);
}